// Round 8
// baseline (594.334 us; speedup 1.0000x reference)
//
#include <hip/hip_runtime.h>

// LSTM B=1024,T=512,F=40,H=50 -- r8: kill the per-step vmcnt(0) barrier drain.
// r5-r7 chains were dominated by the x-stager's global load draining at every
// s_barrier (~500-900 cyc/step). Now: wave 2 bulk-loads 16 timesteps of x into
// an LDS bf16 chunk once per 16 steps (drain amortized 16x), and the B operand
// is split K=128 = [x(40)|pad(24) from chunk] + [h(50)|pad(14) from tiny
// double-buffered panel] -> zero per-step x movement. Pointwise is
// thread-local in the D fragment (gate-interleaved rows' = 4*unit+gate), c in
// VGPR, ONE barrier per step. kMB=2, grid=512 -> 2 chains/CU (r7 win kept).
// GEMM per step: G^T[208,16] = W'[208,128] @ [x|h]^T[128,16], 13 M-tiles
// split 3/3/3/4 over 4 waves, 4 K-chunks -> 52 MFMAs/block-step.

constexpr int kT  = 512;
constexpr int kF  = 40;
constexpr int kH  = 50;
constexpr int kMB = 2;     // real batches per block
constexpr int kCH = 16;    // x-chunk depth (timesteps)

typedef __attribute__((ext_vector_type(8))) short bf16x8;
typedef __attribute__((ext_vector_type(4))) short short4v;
typedef __attribute__((ext_vector_type(4))) float f32x4;

__device__ __forceinline__ unsigned short f2bf(float f) {
    union { float f; unsigned u; } v; v.f = f;
    return (unsigned short)((v.u + 0x7FFFu + ((v.u >> 16) & 1u)) >> 16);
}
__device__ __forceinline__ float fast_sigmoid(float v) {
    return __builtin_amdgcn_rcpf(1.f + __expf(-v));
}
__device__ __forceinline__ float fast_tanh(float v) {
    return 1.f - 2.f * __builtin_amdgcn_rcpf(__expf(2.f * v) + 1.f);
}

__global__ __launch_bounds__(256, 2)
void lstm_mfma_chunk(
    const float* __restrict__ x,      // [B,T,F]
    const float* __restrict__ W_ih,   // [4H,F]
    const float* __restrict__ W_hh,   // [4H,H]
    const float* __restrict__ b_ih,   // [4H]
    const float* __restrict__ b_hh,   // [4H]
    const float* __restrict__ W1,     // [10,H]
    const float* __restrict__ b1,     // [10]
    const float* __restrict__ W2,     // [1,10]
    const float* __restrict__ b2,     // [1]
    float* __restrict__ out)          // [B]
{
    const int tid  = threadIdx.x;
    const int lane = tid & 63;
    const int wave = tid >> 6;
    const int bb   = blockIdx.x;
    const int m16  = lane & 15;    // B/D column = batch (only <kMB real)
    const int q    = lane >> 4;    // quad

    __shared__ short sh_xc[kCH][kMB][64];  // x chunk bf16: k=0..39 real, pad 0
    __shared__ short sh_h[2][kMB][64];     // h panel bf16: k=0..49 real, pad 0
    __shared__ float sh_hf[kMB][52];       // final h fp32
    __shared__ float sh_head[kMB][10];

    const int t0 = (wave == 3) ? 9 : wave * 3;   // first tile of this wave
    const int NT = (wave == 3) ? 4 : 3;          // tiles 3/3/3/4 = 13

    // zero chunk + panel (pads must stay 0 forever)
    { int* z = (int*)sh_xc; for (int i = tid; i < 1024; i += 256) z[i] = 0; }
    { int* z = (int*)sh_h;  for (int i = tid; i <  128; i += 256) z[i] = 0; }

    // ---- A-frag weights (registers), K=128: [x 0..39 |0| h 64..113 |0] ----
    // rows' = 4*unit + gate (i,f,g,o interleaved). A[m=lane&15][k=kk*32+q*8+j].
    bf16x8 wa[4][4];
    float  bias[4][4];
    float  cst[4];
    const int uA = m16 >> 2, gA = m16 & 3;
#pragma unroll
    for (int i = 0; i < 4; ++i) {
        const int tl = t0 + i;
        const int unitA = 4 * tl + uA;
        const bool live = (i < NT) && (unitA < kH);
        const int orow = live ? (unitA + 50 * gA) : 0;
#pragma unroll
        for (int kk = 0; kk < 4; ++kk) {
            bf16x8 v;
#pragma unroll
            for (int j = 0; j < 8; ++j) {
                const int k = kk * 32 + q * 8 + j;
                float wv = 0.f;
                if (live) {
                    if (k < kF)                     wv = W_ih[orow * kF + k];
                    else if (k >= 64 && k < 64+kH)  wv = W_hh[orow * kH + (k - 64)];
                }
                v[j] = (short)f2bf(wv);
            }
            wa[i][kk] = v;
        }
        const int uD = 4 * tl + q;
#pragma unroll
        for (int r = 0; r < 4; ++r)
            bias[i][r] = (i < NT && uD < kH)
                       ? (b_ih[uD + 50 * r] + b_hh[uD + 50 * r]) : 0.f;
        cst[i] = (tl == 0 && q == 0) ? 1.f : 0.f;   // c0[:,0] = 1
    }
    __syncthreads();   // zero-init + panel ready (h0 = 0)

    // ================= time loop: ONE barrier per step =================
    for (int t = 0; t < kT; ++t) {
        if ((t & (kCH - 1)) == 0) {
            // chunk refill: wave 2 loads x[.., t..t+16, :] (320 float4)
            if (wave == 2) {
#pragma unroll
                for (int k5 = 0; k5 < 5; ++k5) {
                    const int idx = lane + 64 * k5;          // 0..319
                    const int m   = idx / 160;
                    const int rem = idx - 160 * m;
                    const int ts  = rem / 10;
                    const int fi  = rem - 10 * ts;
                    float4 v = *(const float4*)(
                        x + ((size_t)(bb * kMB + m) * kT + (t + ts)) * kF + 4 * fi);
                    short4v s;
                    s[0] = (short)f2bf(v.x); s[1] = (short)f2bf(v.y);
                    s[2] = (short)f2bf(v.z); s[3] = (short)f2bf(v.w);
                    *(short4v*)&sh_xc[ts][m][4 * fi] = s;
                }
            }
            __syncthreads();   // drain hits here once per 16 steps
        }

        const int tc  = t & (kCH - 1);
        const int cur = t & 1;
        const bf16x8 z8 = {0,0,0,0,0,0,0,0};
        bf16x8 bx0 = z8, bx1 = z8, bh0 = z8, bh1 = z8;
        if (m16 < kMB) {                           // pad cols supply zeros
            bx0 = *(const bf16x8*)&sh_xc[tc][m16][q * 8];
            bx1 = *(const bf16x8*)&sh_xc[tc][m16][32 + q * 8];
            bh0 = *(const bf16x8*)&sh_h[cur][m16][q * 8];
            bh1 = *(const bf16x8*)&sh_h[cur][m16][32 + q * 8];
        }

#pragma unroll
        for (int i = 0; i < 4; ++i) {
            if (i < NT) {                          // wave-uniform
                f32x4 dx, dh = {0.f, 0.f, 0.f, 0.f};
                dx[0] = bias[i][0]; dx[1] = bias[i][1];
                dx[2] = bias[i][2]; dx[3] = bias[i][3];
                dx = __builtin_amdgcn_mfma_f32_16x16x32_bf16(wa[i][0], bx0, dx, 0, 0, 0);
                dx = __builtin_amdgcn_mfma_f32_16x16x32_bf16(wa[i][1], bx1, dx, 0, 0, 0);
                dh = __builtin_amdgcn_mfma_f32_16x16x32_bf16(wa[i][2], bh0, dh, 0, 0, 0);
                dh = __builtin_amdgcn_mfma_f32_16x16x32_bf16(wa[i][3], bh1, dh, 0, 0, 0);
                // lane holds gates i,f,g,o of (unit 4*tile+q, batch m16)
                if (m16 < kMB) {
                    float i_s = fast_sigmoid(dx[0] + dh[0]);
                    float f_s = fast_sigmoid(dx[1] + dh[1]);
                    float g_t = fast_tanh   (dx[2] + dh[2]);
                    float o_s = fast_sigmoid(dx[3] + dh[3]);
                    float cn  = fmaf(f_s, cst[i], i_s * g_t);
                    cst[i] = cn;
                    float hv = o_s * fast_tanh(cn);
                    const int uD = 4 * (t0 + i) + q;
                    if (uD < kH) {
                        sh_h[cur ^ 1][m16][uD] = (short)f2bf(hv);
                        if (t == kT - 1) sh_hf[m16][uD] = hv;
                    }
                }
            }
        }
        __syncthreads();
    }

    // ---- head: relu(h @ W1.T + b1) @ W2.T + b2 + x[b, T-1, 0] ----
    if (tid < kMB * 10) {
        const int m = tid / 10, j = tid % 10;
        float acc = b1[j];
#pragma unroll
        for (int k = 0; k < kH; ++k) acc = fmaf(sh_hf[m][k], W1[j * kH + k], acc);
        sh_head[m][j] = fmaxf(acc, 0.f);
    }
    __syncthreads();
    if (tid < kMB) {
        float acc = b2[0];
#pragma unroll
        for (int j2 = 0; j2 < 10; ++j2) acc = fmaf(sh_head[tid][j2], W2[j2], acc);
        const int bidx = bb * kMB + tid;
        out[bidx] = acc + x[((size_t)bidx * kT + (kT - 1)) * kF];
    }
}

extern "C" void kernel_launch(void* const* d_in, const int* in_sizes, int n_in,
                              void* d_out, int out_size, void* d_ws, size_t ws_size,
                              hipStream_t stream) {
    const float* x    = (const float*)d_in[0];
    const float* W_ih = (const float*)d_in[1];
    const float* W_hh = (const float*)d_in[2];
    const float* b_ih = (const float*)d_in[3];
    const float* b_hh = (const float*)d_in[4];
    const float* W1   = (const float*)d_in[5];
    const float* b1   = (const float*)d_in[6];
    const float* W2   = (const float*)d_in[7];
    const float* b2   = (const float*)d_in[8];
    float* out = (float*)d_out;

    lstm_mfma_chunk<<<dim3(1024 / kMB), dim3(256), 0, stream>>>(
        x, W_ih, W_hh, b_ih, b_hh, W1, b1, W2, b2, out);
}

// Round 9
// 381.433 us; speedup vs baseline: 1.5582x; 1.5582x over previous
//
#include <hip/hip_runtime.h>

// LSTM B=1024,T=512,F=40,H=50. r9 = r7 (dense pointwise, 2 blocks/CU) +
// chunked x staging (r8 idea, done right) + garbage-tolerant pad columns.
//
// Panel: sh_comb[16 slots][2 batches][104 shorts] = [x(0..39)|h(40..89)|pad].
// x-parts of all 16 slots refilled once per 16 steps from registers that were
// prefetched 16 steps earlier (vmcnt drain 1x/16 steps, ~56 cyc/step
// amortized; r7 paid ~700 cyc EVERY step draining its stager load at the
// barrier). h-part of slot (t+1)&15 written by step t's pointwise.
// GEMM: G^T[208,16] = W'[208,96] @ [x|h]^T[96,16]; rows' = 4*unit+gate;
// 13 M-tiles split 3/3/3/4 over 4 waves, 3 K-chunks -> 39 MFMAs/block-step.
// Pad D-cols 2..15 compute garbage (B rows clamped to m16&1) -- MFMA has no
// cross-column contamination and those cols are never read, so no zeroing and
// no cndmask overhead (r8's VALU inflation). Pointwise DENSE on 100 threads
// (r8's per-tile exec-masked pointwise was 6.5x transcendental issue).

constexpr int kT  = 512;
constexpr int kF  = 40;
constexpr int kH  = 50;
constexpr int kMB = 2;      // real batches per block
constexpr int kCH = 16;     // chunk depth (timesteps)
constexpr int kRowS = 104;  // panel row stride in shorts (208 B)

typedef __attribute__((ext_vector_type(8))) short bf16x8;
typedef __attribute__((ext_vector_type(4))) short short4v;
typedef __attribute__((ext_vector_type(4))) float f32x4;

__device__ __forceinline__ unsigned short f2bf(float f) {
    union { float f; unsigned u; } v; v.f = f;
    return (unsigned short)((v.u + 0x7FFFu + ((v.u >> 16) & 1u)) >> 16);
}
__device__ __forceinline__ float fast_sigmoid(float v) {
    return __builtin_amdgcn_rcpf(1.f + __expf(-v));
}
__device__ __forceinline__ float fast_tanh(float v) {
    return 1.f - 2.f * __builtin_amdgcn_rcpf(__expf(2.f * v) + 1.f);
}

__global__ __launch_bounds__(256, 2)
void lstm_mfma_r9(
    const float* __restrict__ x,      // [B,T,F]
    const float* __restrict__ W_ih,   // [4H,F]
    const float* __restrict__ W_hh,   // [4H,H]
    const float* __restrict__ b_ih,   // [4H]
    const float* __restrict__ b_hh,   // [4H]
    const float* __restrict__ W1,     // [10,H]
    const float* __restrict__ b1,     // [10]
    const float* __restrict__ W2,     // [1,10]
    const float* __restrict__ b2,     // [1]
    float* __restrict__ out)          // [B]
{
    const int tid  = threadIdx.x;
    const int lane = tid & 63;
    const int wave = tid >> 6;
    const int bb   = blockIdx.x;
    const int m16  = lane & 15;    // B/D column = batch (cols >=2 are garbage)
    const int q    = lane >> 4;    // quad

    __shared__ short sh_comb[kCH][kMB][kRowS];  // [x|h|pad] bf16 per slot
    __shared__ float sh_g[kMB][13 * 16];        // gate pre-acts (rows'=4u+r)
    __shared__ float sh_hf[kMB][52];            // final h fp32
    __shared__ float sh_head[kMB][10];

    const int t0 = (wave == 3) ? 9 : wave * 3;  // first tile of this wave
    const int NT = (wave == 3) ? 4 : 3;         // tiles 3/3/3/4 = 13

    // zero the whole panel once (h0 = 0, pads = 0; x overwritten by refill)
    { int* z = (int*)sh_comb; for (int i = tid; i < 1664; i += 256) z[i] = 0; }

    // ---- A-frag weights (registers), K=96: [x 0..39 | h 40..89 | pad] ----
    // rows' = 4*unit + gate.  A[m=lane&15][k = kk*32 + q*8 + j].
    bf16x8 wa[4][3];
    float  bias[4][4];
    const int uA = m16 >> 2, gA = m16 & 3;
#pragma unroll
    for (int i = 0; i < 4; ++i) {
        const int tl = t0 + i;
        const int unitA = 4 * tl + uA;
        const bool live = (i < NT) && (unitA < kH);
        const int orow = live ? (unitA + 50 * gA) : 0;
#pragma unroll
        for (int kk = 0; kk < 3; ++kk) {
            bf16x8 v;
#pragma unroll
            for (int j = 0; j < 8; ++j) {
                const int k = kk * 32 + q * 8 + j;
                float wv = 0.f;
                if (live) {
                    if (k < kF)                     wv = W_ih[orow * kF + k];
                    else if (k < kF + kH)           wv = W_hh[orow * kH + (k - kF)];
                }
                v[j] = (short)f2bf(wv);
            }
            wa[i][kk] = v;
        }
        const int uD = 4 * tl + q;
#pragma unroll
        for (int r = 0; r < 4; ++r)
            bias[i][r] = (i < NT && uD < kH)
                       ? (b_ih[uD + 50 * r] + b_hh[uD + 50 * r]) : 0.f;
    }

    // ---- dense pointwise owners: tid<100 -> (batch pm, unit pu) ----
    const bool pw = (tid < kMB * kH);
    const int  pm = pw ? (tid / kH) : 0;
    const int  pu = pw ? (tid % kH) : 0;
    float c     = (pw && pu == 0) ? 1.f : 0.f;  // c0[:,0] = 1
    float lasth = 0.f;

    // ---- chunk prefetch registers: thread owns float4 idx {tid, tid+256} ----
    // idx: m = idx/160, rem = idx%160, ts = rem/10, fi = rem%10
    float4 pf[2];
    const int idx1 = tid + 256;
#pragma unroll
    for (int r = 0; r < 2; ++r) {
        const int idx = tid + 256 * r;
        if (idx < 320) {
            const int m = idx / 160, rem = idx % 160;
            const int ts = rem / 10, fi = rem % 10;
            pf[r] = *(const float4*)(
                x + ((size_t)(bb * kMB + m) * kT + ts) * kF + 4 * fi);
        }
    }

    // ================= time loop =================
    for (int t = 0; t < kT; ++t) {
        const int tc = t & (kCH - 1);

        if (tc == 0) {
            // commit prefetched chunk (x parts of all 16 slots)
#pragma unroll
            for (int r = 0; r < 2; ++r) {
                const int idx = tid + 256 * r;
                if (idx < 320) {
                    const int m = idx / 160, rem = idx % 160;
                    const int ts = rem / 10, fi = rem % 10;
                    short4v s;
                    s[0] = (short)f2bf(pf[r].x); s[1] = (short)f2bf(pf[r].y);
                    s[2] = (short)f2bf(pf[r].z); s[3] = (short)f2bf(pf[r].w);
                    *(short4v*)&sh_comb[ts][m][4 * fi] = s;
                }
            }
            __syncthreads();
            // issue next chunk's loads (in flight for the next 16 steps)
            if (t + kCH < kT) {
#pragma unroll
                for (int r = 0; r < 2; ++r) {
                    const int idx = tid + 256 * r;
                    if (idx < 320) {
                        const int m = idx / 160, rem = idx % 160;
                        const int ts = rem / 10, fi = rem % 10;
                        pf[r] = *(const float4*)(
                            x + ((size_t)(bb * kMB + m) * kT + (t + kCH + ts)) * kF + 4 * fi);
                    }
                }
            }
        }

        // B fragments: all lanes read row m16&1 (cols 2..15 produce garbage
        // in D cols we never read -- no cross-column contamination in MFMA)
        const short* rowp = &sh_comb[tc][m16 & 1][0];
        bf16x8 bv0 = *(const bf16x8*)(rowp +      q * 8);
        bf16x8 bv1 = *(const bf16x8*)(rowp + 32 + q * 8);
        bf16x8 bv2 = *(const bf16x8*)(rowp + 64 + q * 8);

#pragma unroll
        for (int i = 0; i < 4; ++i) {
            if (i < NT) {                          // wave-uniform
                f32x4 d;
                d[0] = bias[i][0]; d[1] = bias[i][1];
                d[2] = bias[i][2]; d[3] = bias[i][3];
                d = __builtin_amdgcn_mfma_f32_16x16x32_bf16(wa[i][0], bv0, d, 0, 0, 0);
                d = __builtin_amdgcn_mfma_f32_16x16x32_bf16(wa[i][1], bv1, d, 0, 0, 0);
                d = __builtin_amdgcn_mfma_f32_16x16x32_bf16(wa[i][2], bv2, d, 0, 0, 0);
                if (m16 < kMB)                     // 2 real cols only
                    *(f32x4*)&sh_g[m16][16 * (t0 + i) + 4 * q] = d;
            }
        }
        __syncthreads();                           // sh_g ready

        if (pw) {
            f32x4 g = *(const f32x4*)&sh_g[pm][4 * pu];  // i,f,g,o of unit pu
            float i_s = fast_sigmoid(g[0]);
            float f_s = fast_sigmoid(g[1]);
            float g_t = fast_tanh   (g[2]);
            float o_s = fast_sigmoid(g[3]);
            c = fmaf(f_s, c, i_s * g_t);
            lasth = o_s * fast_tanh(c);
            // h_{t+1} into the h-part of slot (t+1)&15 (x-part untouched)
            sh_comb[(t + 1) & (kCH - 1)][pm][kF + pu] = (short)f2bf(lasth);
        }
        __syncthreads();                           // panel ready for t+1
    }

    // ---- head: relu(h @ W1.T + b1) @ W2.T + b2 + x[b, T-1, 0] ----
    if (pw) sh_hf[pm][pu] = lasth;
    __syncthreads();
    if (tid < kMB * 10) {
        const int m = tid / 10, j = tid % 10;
        float acc = b1[j];
#pragma unroll
        for (int k = 0; k < kH; ++k) acc = fmaf(sh_hf[m][k], W1[j * kH + k], acc);
        sh_head[m][j] = fmaxf(acc, 0.f);
    }
    __syncthreads();
    if (tid < kMB) {
        float acc = b2[0];
#pragma unroll
        for (int j2 = 0; j2 < 10; ++j2) acc = fmaf(sh_head[tid][j2], W2[j2], acc);
        const int bidx = bb * kMB + tid;
        out[bidx] = acc + x[((size_t)bidx * kT + (kT - 1)) * kF];
    }
}

extern "C" void kernel_launch(void* const* d_in, const int* in_sizes, int n_in,
                              void* d_out, int out_size, void* d_ws, size_t ws_size,
                              hipStream_t stream) {
    const float* x    = (const float*)d_in[0];
    const float* W_ih = (const float*)d_in[1];
    const float* W_hh = (const float*)d_in[2];
    const float* b_ih = (const float*)d_in[3];
    const float* b_hh = (const float*)d_in[4];
    const float* W1   = (const float*)d_in[5];
    const float* b1   = (const float*)d_in[6];
    const float* W2   = (const float*)d_in[7];
    const float* b2   = (const float*)d_in[8];
    float* out = (float*)d_out;

    lstm_mfma_r9<<<dim3(1024 / kMB), dim3(256), 0, stream>>>(
        x, W_ih, W_hh, b_ih, b_hh, W1, b1, W2, b2, out);
}